// Round 1
// baseline (725.995 us; speedup 1.0000x reference)
//
#include <hip/hip_runtime.h>

// TreeLSTM via bf16 hi/lo split-precision MFMA (CDNA4 has no fp32 MFMA).
// A*B ~= Ah*Bh + Ah*Bl + Al*Bh in fp32 accumulators: ~1e-4 abs accuracy.
// Kernel 1 packs the 8 weight matrices into MFMA B-fragment order (hi/lo)
// in the workspace; kernel 2 does the fused forward pass.

typedef __attribute__((ext_vector_type(8))) __bf16 bf16x8;
typedef __attribute__((ext_vector_type(4))) float f32x4;

namespace {
constexpr int kK = 8;     // children
constexpr int kD = 128;   // input dim
constexpr int kH = 128;   // hidden dim
constexpr int kM = 16;    // nodes per block
constexpr int kBlk = 512; // 8 waves; wave w owns output columns [16w,16w+16)

// LDS layout (bytes). child split: [128 rows][128] bf16 per half, row=n*8+k.
constexpr int CH_HI = 0;
constexpr int CH_LO = 32768;
constexpr int HS_HI = 65536;  // h_sum split [16][128]
constexpr int HS_LO = 69632;
constexpr int XS_HI = 73728;  // x split [16][128]
constexpr int XS_LO = 77824;
constexpr int GSTRIDE = 132;  // padded fp32 gate rows (bank-conflict)
constexpr int G_IU = 81920;   // i*u   [16][132] f32
constexpr int G_O  = G_IU + 16 * GSTRIDE * 4;
constexpr int G_FX = G_O  + 16 * GSTRIDE * 4;
constexpr int SMEM_SZ = G_FX + 16 * GSTRIDE * 4;  // 107264 B -> 1 block/CU
}

__device__ __forceinline__ unsigned f2bf(float f) {  // RNE f32 -> bf16 bits
  unsigned u = __float_as_uint(f);
  return (u + 0x7fffu + ((u >> 16) & 1u)) >> 16;
}
__device__ __forceinline__ float bf2f(unsigned h) {
  return __uint_as_float(h << 16);
}
__device__ __forceinline__ float sig_(float z) {
  return 1.0f / (1.0f + __expf(-z));
}
__device__ __forceinline__ float th_(float z) {
  return 1.0f - 2.0f / (__expf(2.0f * z) + 1.0f);
}
__device__ __forceinline__ f32x4 mfma16(bf16x8 a, bf16x8 b, f32x4 c) {
  return __builtin_amdgcn_mfma_f32_16x16x32_bf16(a, b, c, 0, 0, 0);
}

// XOR swizzle: 16B-slot index within a 256B row XORed with (row&15) so that
// fragment reads (16 lanes x same k-slot, different rows) spread banks.
__device__ __forceinline__ int swzOff(int row, int kByte) {
  return row * 256 + (kByte ^ ((row & 15) << 4));
}

__device__ __forceinline__ void split8(const float4& a, const float4& b,
                                       uint4& hi, uint4& lo) {
  const unsigned h0 = f2bf(a.x), h1 = f2bf(a.y), h2 = f2bf(a.z), h3 = f2bf(a.w);
  const unsigned h4 = f2bf(b.x), h5 = f2bf(b.y), h6 = f2bf(b.z), h7 = f2bf(b.w);
  hi = make_uint4(h0 | (h1 << 16), h2 | (h3 << 16), h4 | (h5 << 16),
                  h6 | (h7 << 16));
  const unsigned l0 = f2bf(a.x - bf2f(h0)), l1 = f2bf(a.y - bf2f(h1));
  const unsigned l2 = f2bf(a.z - bf2f(h2)), l3 = f2bf(a.w - bf2f(h3));
  const unsigned l4 = f2bf(b.x - bf2f(h4)), l5 = f2bf(b.y - bf2f(h5));
  const unsigned l6 = f2bf(b.z - bf2f(h6)), l7 = f2bf(b.w - bf2f(h7));
  lo = make_uint4(l0 | (l1 << 16), l2 | (l3 << 16), l4 | (l5 << 16),
                  l6 | (l7 << 16));
}

__device__ __forceinline__ void store_split4(const float4& v, void* hp,
                                             void* lp) {
  const unsigned h0 = f2bf(v.x), h1 = f2bf(v.y), h2 = f2bf(v.z), h3 = f2bf(v.w);
  *reinterpret_cast<uint2*>(hp) = make_uint2(h0 | (h1 << 16), h2 | (h3 << 16));
  const unsigned l0 = f2bf(v.x - bf2f(h0)), l1 = f2bf(v.y - bf2f(h1));
  const unsigned l2 = f2bf(v.z - bf2f(h2)), l3 = f2bf(v.w - bf2f(h3));
  *reinterpret_cast<uint2*>(lp) = make_uint2(l0 | (l1 << 16), l2 | (l3 << 16));
}

__device__ __forceinline__ bf16x8 ldfrag(const unsigned char* base, int row,
                                         int kB) {
  return __builtin_bit_cast(
      bf16x8, *reinterpret_cast<const uint4*>(base + swzOff(row, kB)));
}

// ---------------------------------------------------------------------------
// Kernel 1: pack 8 weight matrices [128][128] f32 into MFMA B-fragments.
// Fragment (mat m, colblock cb, kstep s, half): 64 lanes x 16B; lane holds
// B[k = s*32 + 8*(lane>>4) + e][col = cb*16 + (lane&15)], e=0..7.
// Index: ((((m*8+cb)*4+s)*2+half)*64 + lane) uint4s.
// ---------------------------------------------------------------------------
__global__ __launch_bounds__(256) void pack_weights(
    const float* __restrict__ Wi, const float* __restrict__ Wo,
    const float* __restrict__ Wu, const float* __restrict__ Wf,
    const float* __restrict__ Ui, const float* __restrict__ Uo,
    const float* __restrict__ Uu, const float* __restrict__ Uf,
    uint4* __restrict__ out) {
  const int gid = blockIdx.x * 256 + threadIdx.x;  // 32768 total
  const int lane = gid & 63;
  const int fid = gid >> 6;  // 0..511
  const int half = fid & 1;
  const int s = (fid >> 1) & 3;
  const int cb = (fid >> 3) & 7;
  const int m = fid >> 6;  // 0..7
  const float* mats[8] = {Wi, Wo, Wu, Wf, Ui, Uo, Uu, Uf};
  const float* W = mats[m];
  const int col = cb * 16 + (lane & 15);
  const int k0 = s * 32 + 8 * (lane >> 4);
  unsigned r[8];
#pragma unroll
  for (int e = 0; e < 8; ++e) {
    const float v = W[(k0 + e) * kH + col];
    const unsigned hb = f2bf(v);
    r[e] = half ? f2bf(v - bf2f(hb)) : hb;
  }
  out[gid] = make_uint4(r[0] | (r[1] << 16), r[2] | (r[3] << 16),
                        r[4] | (r[5] << 16), r[6] | (r[7] << 16));
}

// ---------------------------------------------------------------------------
// Kernel 2: fused TreeLSTM. 16 nodes/block, 512 threads (8 waves).
// ---------------------------------------------------------------------------
__global__ __launch_bounds__(kBlk, 2) void treelstm_mfma(
    const float* __restrict__ x, const float* __restrict__ child_h,
    const float* __restrict__ child_c, const float* __restrict__ bi,
    const float* __restrict__ bo, const float* __restrict__ bu,
    const float* __restrict__ bfg, const uint4* __restrict__ wp,
    float* __restrict__ h_out, float* __restrict__ c_out) {
  __shared__ alignas(16) unsigned char smem[SMEM_SZ];
  const int t = threadIdx.x;
  const int n0 = blockIdx.x * kM;

  // ---- Stage child_h: coalesced f32 loads, split to bf16 hi/lo in LDS ----
  {
    const float* cbase = child_h + (size_t)n0 * (kK * kH);
#pragma unroll
    for (int i = 0; i < 4; ++i) {
      const int c8 = i * kBlk + t;  // chunk of 8 contiguous floats, 0..2047
      const int row = c8 >> 4;      // (node*8 + k), 0..127
      const int j8 = c8 & 15;
      const float4* src =
          reinterpret_cast<const float4*>(cbase + row * kH + j8 * 8);
      const float4 a = src[0], b = src[1];
      uint4 hi, lo;
      split8(a, b, hi, lo);
      const int off = swzOff(row, j8 * 16);
      *reinterpret_cast<uint4*>(smem + CH_HI + off) = hi;
      *reinterpret_cast<uint4*>(smem + CH_LO + off) = lo;
    }
  }
  // ---- h_sum (fp32, from L1-hot re-read) and x: split into LDS ----
  {
    const int nl = t >> 5, d4 = t & 31;
    const float* base = child_h + ((size_t)(n0 + nl) * kK) * kH + d4 * 4;
    float4 s = *reinterpret_cast<const float4*>(base);
#pragma unroll
    for (int k = 1; k < kK; ++k) {
      const float4 v = *reinterpret_cast<const float4*>(base + k * kH);
      s.x += v.x; s.y += v.y; s.z += v.z; s.w += v.w;
    }
    const int off = swzOff(nl, d4 * 8);
    store_split4(s, smem + HS_HI + off, smem + HS_LO + off);
    const float4 xv =
        *reinterpret_cast<const float4*>(x + (size_t)(n0 + nl) * kD + d4 * 4);
    store_split4(xv, smem + XS_HI + off, smem + XS_LO + off);
  }
  __syncthreads();

  const int w = t >> 6;  // wave id == output column block
  const int l = t & 63;
  const int lr = l & 15;
  const int lg = l >> 4;
  const int col = w * 16 + lr;

  float* g_iu = reinterpret_cast<float*>(smem + G_IU);
  float* g_o  = reinterpret_cast<float*>(smem + G_O);
  float* g_fx = reinterpret_cast<float*>(smem + G_FX);

  // ---- Pass A: 7 gate GEMMs for this wave's 16 columns ----
  const float biv = bi[col], bov = bo[col], buv = bu[col], bfv = bfg[col];
  f32x4 acc[7];
#pragma unroll
  for (int m = 0; m < 7; ++m) acc[m] = f32x4{0.f, 0.f, 0.f, 0.f};

#pragma unroll
  for (int s = 0; s < 4; ++s) {
    const int kB = s * 64 + lg * 16;
    const bf16x8 axh = ldfrag(smem + XS_HI, lr, kB);
    const bf16x8 axl = ldfrag(smem + XS_LO, lr, kB);
    const bf16x8 ahh = ldfrag(smem + HS_HI, lr, kB);
    const bf16x8 ahl = ldfrag(smem + HS_LO, lr, kB);
#pragma unroll
    for (int m = 0; m < 7; ++m) {  // 0..3: Wi,Wo,Wu,Wf (x); 4..6: Ui,Uo,Uu
      const uint4* bp = wp + ((((m * 8 + w) * 4 + s) * 2) * 64) + l;
      const bf16x8 Bh = __builtin_bit_cast(bf16x8, bp[0]);
      const bf16x8 Bl = __builtin_bit_cast(bf16x8, bp[64]);
      const bf16x8 Ah = (m < 4) ? axh : ahh;
      const bf16x8 Al = (m < 4) ? axl : ahl;
      acc[m] = mfma16(Ah, Bh, acc[m]);
      acc[m] = mfma16(Ah, Bl, acc[m]);
      acc[m] = mfma16(Al, Bh, acc[m]);
    }
  }
  // D layout: col = lane&15, row(node) = 4*(lane>>4)+q  [m89-verified]
#pragma unroll
  for (int q = 0; q < 4; ++q) {
    const int nr = 4 * lg + q;
    const float iv = sig_(acc[0][q] + acc[4][q] + biv);
    const float ov = sig_(acc[1][q] + acc[5][q] + bov);
    const float uv = th_(acc[2][q] + acc[6][q] + buv);
    g_iu[nr * GSTRIDE + col] = iv * uv;
    g_o [nr * GSTRIDE + col] = ov;
    g_fx[nr * GSTRIDE + col] = acc[3][q] + bfv;
  }
  __syncthreads();

  // ---- Pass B: child_h @ Uf, fused f-gate, c/h epilogue ----
  bf16x8 Uh[4], Ul[4];  // Uf fragments register-resident (mat 7)
#pragma unroll
  for (int s = 0; s < 4; ++s) {
    const uint4* bp = wp + ((((7 * 8 + w) * 4 + s) * 2) * 64) + l;
    Uh[s] = __builtin_bit_cast(bf16x8, bp[0]);
    Ul[s] = __builtin_bit_cast(bf16x8, bp[64]);
  }
#pragma unroll
  for (int r2 = 0; r2 < 8; r2 += 2) {  // two 16-row tiles per iter (ILP)
    f32x4 dA = f32x4{0.f, 0.f, 0.f, 0.f};
    f32x4 dB = f32x4{0.f, 0.f, 0.f, 0.f};
#pragma unroll
    for (int s = 0; s < 4; ++s) {
      const int kB = s * 64 + lg * 16;
      const bf16x8 a0h = ldfrag(smem + CH_HI, r2 * 16 + lr, kB);
      const bf16x8 a0l = ldfrag(smem + CH_LO, r2 * 16 + lr, kB);
      const bf16x8 a1h = ldfrag(smem + CH_HI, r2 * 16 + 16 + lr, kB);
      const bf16x8 a1l = ldfrag(smem + CH_LO, r2 * 16 + 16 + lr, kB);
      dA = mfma16(a0h, Uh[s], dA);
      dB = mfma16(a1h, Uh[s], dB);
      dA = mfma16(a0h, Ul[s], dA);
      dB = mfma16(a1h, Ul[s], dB);
      dA = mfma16(a0l, Uh[s], dA);
      dB = mfma16(a1l, Uh[s], dB);
    }
#pragma unroll
    for (int hh = 0; hh < 2; ++hh) {
      const f32x4 d = hh ? dB : dA;
      const int rb = r2 + hh;
      // tile row = 4*lg+q -> node = 2*rb + (lg>>1), child k = 4*(lg&1)+q
      const int nloc = 2 * rb + (lg >> 1);
      const int kbase = 4 * (lg & 1);
      const float fxv = g_fx[nloc * GSTRIDE + col];
      const float* ccp =
          child_c + ((size_t)(n0 + nloc) * kK + kbase) * kH + col;
      float cp = 0.f;
#pragma unroll
      for (int q = 0; q < 4; ++q)
        cp = fmaf(sig_(d[q] + fxv), ccp[q * kH], cp);
      cp += __shfl_xor(cp, 16);  // join k halves (lg pairs 0<->1, 2<->3)
      const float cv = g_iu[nloc * GSTRIDE + col] + cp;
      const float hv = g_o[nloc * GSTRIDE + col] * th_(cv);
      const size_t go = (size_t)(n0 + nloc) * kH + col;
      if ((lg & 1) == 0) h_out[go] = hv;  // lg 0,2 write h
      else               c_out[go] = cv;  // lg 1,3 write c (same value)
    }
  }
}

extern "C" void kernel_launch(void* const* d_in, const int* in_sizes, int n_in,
                              void* d_out, int out_size, void* d_ws,
                              size_t ws_size, hipStream_t stream) {
  const float* x       = (const float*)d_in[0];
  const float* child_h = (const float*)d_in[1];
  const float* child_c = (const float*)d_in[2];
  const float* Wi = (const float*)d_in[3];
  const float* bi = (const float*)d_in[4];
  const float* Ui = (const float*)d_in[5];
  const float* Wo = (const float*)d_in[6];
  const float* bo = (const float*)d_in[7];
  const float* Uo = (const float*)d_in[8];
  const float* Wu = (const float*)d_in[9];
  const float* bu = (const float*)d_in[10];
  const float* Uu = (const float*)d_in[11];
  const float* Wf = (const float*)d_in[12];
  const float* bf = (const float*)d_in[13];
  const float* Uf = (const float*)d_in[14];
  (void)n_in; (void)out_size; (void)ws_size;

  const int n = in_sizes[0] / kD;  // 65536
  float* h_out = (float*)d_out;
  float* c_out = h_out + (size_t)n * kH;
  uint4* wpack = (uint4*)d_ws;  // 512 KiB packed weights

  pack_weights<<<128, 256, 0, stream>>>(Wi, Wo, Wu, Wf, Ui, Uo, Uu, Uf, wpack);
  treelstm_mfma<<<n / kM, kBlk, 0, stream>>>(x, child_h, child_c, bi, bo, bu,
                                             bf, wpack, h_out, c_out);
}

// Round 2
// 722.325 us; speedup vs baseline: 1.0051x; 1.0051x over previous
//
#include <hip/hip_runtime.h>

// TreeLSTM via bf16 hi/lo split-precision MFMA (CDNA4 has no fp32 MFMA).
// A*B ~= Ah*Bh + Ah*Bl + Al*Bh in fp32 accumulators.
// v2: LDS cut 107KB -> 41KB (occupancy 1 -> 2-3 blocks/CU). Pass B is
// row-split per wave; child_h A-fragments are loaded per-lane from global
// (L1-hot) and split in-register with exact truncation (bit ops only).

typedef __attribute__((ext_vector_type(8))) __bf16 bf16x8;
typedef __attribute__((ext_vector_type(4))) float f32x4;

namespace {
constexpr int kK = 8;     // children
constexpr int kD = 128;   // input dim
constexpr int kH = 128;   // hidden dim
constexpr int kM = 16;    // nodes per block
constexpr int kBlk = 512; // 8 waves

// LDS layout (bytes).
constexpr int HS_HI = 0;      // h_sum split [16][128] bf16, swizzled
constexpr int HS_LO = 4096;
constexpr int XS_HI = 8192;   // x split [16][128] bf16, swizzled
constexpr int XS_LO = 12288;
constexpr int GSTRIDE = 132;  // padded fp32 gate rows
constexpr int G_IU = 16384;   // i*u  [16][132] f32
constexpr int G_O  = G_IU + 16 * GSTRIDE * 4;
constexpr int G_FX = G_O  + 16 * GSTRIDE * 4;
constexpr int SMEM_SZ = G_FX + 16 * GSTRIDE * 4;  // 41728 B -> 3 blocks by LDS
}

__device__ __forceinline__ unsigned f2bf(float f) {  // RNE f32 -> bf16 bits
  unsigned u = __float_as_uint(f);
  return (u + 0x7fffu + ((u >> 16) & 1u)) >> 16;
}
__device__ __forceinline__ float bf2f(unsigned h) {
  return __uint_as_float(h << 16);
}
__device__ __forceinline__ float sig_(float z) {
  return 1.0f / (1.0f + __expf(-z));
}
__device__ __forceinline__ float th_(float z) {
  return 1.0f - 2.0f / (__expf(2.0f * z) + 1.0f);
}
__device__ __forceinline__ f32x4 mfma16(bf16x8 a, bf16x8 b, f32x4 c) {
  return __builtin_amdgcn_mfma_f32_16x16x32_bf16(a, b, c, 0, 0, 0);
}

// XOR swizzle: 16B-slot index within a 256B row XORed with (row&15).
__device__ __forceinline__ int swzOff(int row, int kByte) {
  return row * 256 + (kByte ^ ((row & 15) << 4));
}

__device__ __forceinline__ void store_split4(const float4& v, void* hp,
                                             void* lp) {
  const unsigned h0 = f2bf(v.x), h1 = f2bf(v.y), h2 = f2bf(v.z), h3 = f2bf(v.w);
  *reinterpret_cast<uint2*>(hp) = make_uint2(h0 | (h1 << 16), h2 | (h3 << 16));
  const unsigned l0 = f2bf(v.x - bf2f(h0)), l1 = f2bf(v.y - bf2f(h1));
  const unsigned l2 = f2bf(v.z - bf2f(h2)), l3 = f2bf(v.w - bf2f(h3));
  *reinterpret_cast<uint2*>(lp) = make_uint2(l0 | (l1 << 16), l2 | (l3 << 16));
}

// Truncation split: hi = chop(x) (exact bit-and), lo = x - hi (exact fp32),
// lo chopped to bf16. Total error ~2^-16 relative; residual term Al*Bh kept.
__device__ __forceinline__ void tsplit8(const float4& a, const float4& b,
                                        bf16x8& hi, bf16x8& lo) {
  const float fa[8] = {a.x, a.y, a.z, a.w, b.x, b.y, b.z, b.w};
  unsigned hu[4], lu[4];
#pragma unroll
  for (int p = 0; p < 4; ++p) {
    const unsigned u0 = __float_as_uint(fa[2 * p]);
    const unsigned u1 = __float_as_uint(fa[2 * p + 1]);
    hu[p] = (u0 >> 16) | (u1 & 0xffff0000u);
    const float l0 = fa[2 * p]     - __uint_as_float(u0 & 0xffff0000u);
    const float l1 = fa[2 * p + 1] - __uint_as_float(u1 & 0xffff0000u);
    lu[p] = (__float_as_uint(l0) >> 16) | (__float_as_uint(l1) & 0xffff0000u);
  }
  hi = __builtin_bit_cast(bf16x8, make_uint4(hu[0], hu[1], hu[2], hu[3]));
  lo = __builtin_bit_cast(bf16x8, make_uint4(lu[0], lu[1], lu[2], lu[3]));
}

__device__ __forceinline__ bf16x8 ldfrag(const unsigned char* base, int row,
                                         int kB) {
  return __builtin_bit_cast(
      bf16x8, *reinterpret_cast<const uint4*>(base + swzOff(row, kB)));
}

// ---------------------------------------------------------------------------
// Kernel 1: pack 8 weight matrices [128][128] f32 into MFMA B-fragments.
// Fragment (mat m, colblock cb, kstep s, half): 64 lanes x 16B; lane holds
// B[k = s*32 + 8*(lane>>4) + e][col = cb*16 + (lane&15)], e=0..7.
// Index: ((((m*8+cb)*4+s)*2+half)*64 + lane) uint4s.
// ---------------------------------------------------------------------------
__global__ __launch_bounds__(256) void pack_weights(
    const float* __restrict__ Wi, const float* __restrict__ Wo,
    const float* __restrict__ Wu, const float* __restrict__ Wf,
    const float* __restrict__ Ui, const float* __restrict__ Uo,
    const float* __restrict__ Uu, const float* __restrict__ Uf,
    uint4* __restrict__ out) {
  const int gid = blockIdx.x * 256 + threadIdx.x;  // 32768 total
  const int lane = gid & 63;
  const int fid = gid >> 6;  // 0..511
  const int half = fid & 1;
  const int s = (fid >> 1) & 3;
  const int cb = (fid >> 3) & 7;
  const int m = fid >> 6;  // 0..7
  const float* mats[8] = {Wi, Wo, Wu, Wf, Ui, Uo, Uu, Uf};
  const float* W = mats[m];
  const int col = cb * 16 + (lane & 15);
  const int k0 = s * 32 + 8 * (lane >> 4);
  unsigned r[8];
#pragma unroll
  for (int e = 0; e < 8; ++e) {
    const float v = W[(k0 + e) * kH + col];
    const unsigned hb = f2bf(v);
    r[e] = half ? f2bf(v - bf2f(hb)) : hb;
  }
  out[gid] = make_uint4(r[0] | (r[1] << 16), r[2] | (r[3] << 16),
                        r[4] | (r[5] << 16), r[6] | (r[7] << 16));
}

// ---------------------------------------------------------------------------
// Kernel 2: fused TreeLSTM. 16 nodes/block, 512 threads (8 waves).
// ---------------------------------------------------------------------------
__global__ __launch_bounds__(kBlk, 4) void treelstm_mfma(
    const float* __restrict__ x, const float* __restrict__ child_h,
    const float* __restrict__ child_c, const float* __restrict__ bi,
    const float* __restrict__ bo, const float* __restrict__ bu,
    const float* __restrict__ bfg, const uint4* __restrict__ wp,
    float* __restrict__ h_out, float* __restrict__ c_out) {
  __shared__ alignas(16) unsigned char smem[SMEM_SZ];
  const int t = threadIdx.x;
  const int n0 = blockIdx.x * kM;

  // ---- Stage h_sum (fp32 accumulate from global) and x: split into LDS ----
  {
    const int nl = t >> 5, d4 = t & 31;
    const float* base = child_h + ((size_t)(n0 + nl) * kK) * kH + d4 * 4;
    float4 s = *reinterpret_cast<const float4*>(base);
#pragma unroll
    for (int k = 1; k < kK; ++k) {
      const float4 v = *reinterpret_cast<const float4*>(base + k * kH);
      s.x += v.x; s.y += v.y; s.z += v.z; s.w += v.w;
    }
    const int off = swzOff(nl, d4 * 8);
    store_split4(s, smem + HS_HI + off, smem + HS_LO + off);
    const float4 xv =
        *reinterpret_cast<const float4*>(x + (size_t)(n0 + nl) * kD + d4 * 4);
    store_split4(xv, smem + XS_HI + off, smem + XS_LO + off);
  }
  __syncthreads();

  const int w = t >> 6;  // wave id
  const int l = t & 63;
  const int lr = l & 15;
  const int lg = l >> 4;

  float* g_iu = reinterpret_cast<float*>(smem + G_IU);
  float* g_o  = reinterpret_cast<float*>(smem + G_O);
  float* g_fx = reinterpret_cast<float*>(smem + G_FX);

  // ---- Pass A: 7 gate GEMMs; wave w owns output columns [16w,16w+16) ----
  {
    const int col = w * 16 + lr;
    const float biv = bi[col], bov = bo[col], buv = bu[col], bfv = bfg[col];
    f32x4 acc[7];
#pragma unroll
    for (int m = 0; m < 7; ++m) acc[m] = f32x4{0.f, 0.f, 0.f, 0.f};

#pragma unroll
    for (int s = 0; s < 4; ++s) {
      const int kB = s * 64 + lg * 16;
      const bf16x8 axh = ldfrag(smem + XS_HI, lr, kB);
      const bf16x8 axl = ldfrag(smem + XS_LO, lr, kB);
      const bf16x8 ahh = ldfrag(smem + HS_HI, lr, kB);
      const bf16x8 ahl = ldfrag(smem + HS_LO, lr, kB);
#pragma unroll
      for (int m = 0; m < 7; ++m) {  // 0..3: Wi,Wo,Wu,Wf (x); 4..6: Ui,Uo,Uu
        const uint4* bp = wp + ((((m * 8 + w) * 4 + s) * 2) * 64) + l;
        const bf16x8 Bh = __builtin_bit_cast(bf16x8, bp[0]);
        const bf16x8 Bl = __builtin_bit_cast(bf16x8, bp[64]);
        const bf16x8 Ah = (m < 4) ? axh : ahh;
        const bf16x8 Al = (m < 4) ? axl : ahl;
        acc[m] = mfma16(Ah, Bh, acc[m]);
        acc[m] = mfma16(Ah, Bl, acc[m]);
        acc[m] = mfma16(Al, Bh, acc[m]);
      }
    }
    // D layout: col = lane&15, row(node) = 4*(lane>>4)+q
#pragma unroll
    for (int q = 0; q < 4; ++q) {
      const int nr = 4 * lg + q;
      const float iv = sig_(acc[0][q] + acc[4][q] + biv);
      const float ov = sig_(acc[1][q] + acc[5][q] + bov);
      const float uv = th_(acc[2][q] + acc[6][q] + buv);
      g_iu[nr * GSTRIDE + col] = iv * uv;
      g_o [nr * GSTRIDE + col] = ov;
      g_fx[nr * GSTRIDE + col] = acc[3][q] + bfv;
    }
  }
  __syncthreads();

  // ---- Pass B: child_h @ Uf (row-split: wave w owns child rows 16w..16w+15,
  //      i.e. nodes 2w,2w+1), iterating all 8 column blocks. ----
  bf16x8 AH[4], AL[4];
  {
    // Lane's A-fragment row = 16w + lr; k-slice = s*32 + 8*lg .. +8.
    const float* abase =
        child_h + ((size_t)n0 * kK + 16 * w + lr) * kH + lg * 8;
#pragma unroll
    for (int s = 0; s < 4; ++s) {
      const float4 a = *reinterpret_cast<const float4*>(abase + s * 32);
      const float4 b = *reinterpret_cast<const float4*>(abase + s * 32 + 4);
      tsplit8(a, b, AH[s], AL[s]);
    }
  }
  // D tile row = 4*lg+q -> node_local = 2w + (lg>>1), child k = 4*(lg&1)+q
  const int nl0 = 2 * w + (lg >> 1);
  const int kb0 = 4 * (lg & 1);
  const size_t ccrow = ((size_t)(n0 + nl0) * kK + kb0) * kH;

#pragma unroll
  for (int cb = 0; cb < 8; ++cb) {
    const uint4* bp = wp + (((7 * 8 + cb) * 4) * 2) * 64 + l;  // Uf, colblk cb
    f32x4 d = f32x4{0.f, 0.f, 0.f, 0.f};
#pragma unroll
    for (int s = 0; s < 4; ++s) {
      const bf16x8 Bh = __builtin_bit_cast(bf16x8, bp[s * 128]);
      const bf16x8 Bl = __builtin_bit_cast(bf16x8, bp[s * 128 + 64]);
      d = mfma16(AH[s], Bh, d);
      d = mfma16(AH[s], Bl, d);
      d = mfma16(AL[s], Bh, d);
    }
    const int col = cb * 16 + lr;
    const float fxv = g_fx[nl0 * GSTRIDE + col];
    const float* ccp = child_c + ccrow + col;
    float cp = 0.f;
#pragma unroll
    for (int q = 0; q < 4; ++q)
      cp = fmaf(sig_(d[q] + fxv), ccp[q * kH], cp);
    cp += __shfl_xor(cp, 16);  // join k halves (lg pairs 0<->1, 2<->3)
    const float cv = g_iu[nl0 * GSTRIDE + col] + cp;
    const float hv = g_o[nl0 * GSTRIDE + col] * th_(cv);
    const size_t go = (size_t)(n0 + nl0) * kH + col;
    if ((lg & 1) == 0) h_out[go] = hv;  // lg 0,2 write h
    else               c_out[go] = cv;  // lg 1,3 write c (same value)
  }
}

extern "C" void kernel_launch(void* const* d_in, const int* in_sizes, int n_in,
                              void* d_out, int out_size, void* d_ws,
                              size_t ws_size, hipStream_t stream) {
  const float* x       = (const float*)d_in[0];
  const float* child_h = (const float*)d_in[1];
  const float* child_c = (const float*)d_in[2];
  const float* Wi = (const float*)d_in[3];
  const float* bi = (const float*)d_in[4];
  const float* Ui = (const float*)d_in[5];
  const float* Wo = (const float*)d_in[6];
  const float* bo = (const float*)d_in[7];
  const float* Uo = (const float*)d_in[8];
  const float* Wu = (const float*)d_in[9];
  const float* bu = (const float*)d_in[10];
  const float* Uu = (const float*)d_in[11];
  const float* Wf = (const float*)d_in[12];
  const float* bf = (const float*)d_in[13];
  const float* Uf = (const float*)d_in[14];
  (void)n_in; (void)out_size; (void)ws_size;

  const int n = in_sizes[0] / kD;  // 65536
  float* h_out = (float*)d_out;
  float* c_out = h_out + (size_t)n * kH;
  uint4* wpack = (uint4*)d_ws;  // 512 KiB packed weights

  pack_weights<<<128, 256, 0, stream>>>(Wi, Wo, Wu, Wf, Ui, Uo, Uu, Uf, wpack);
  treelstm_mfma<<<n / kM, kBlk, 0, stream>>>(x, child_h, child_c, bi, bo, bu,
                                             bf, wpack, h_out, c_out);
}